// Round 2
// baseline (1207.682 us; speedup 1.0000x reference)
//
#include <hip/hip_runtime.h>
#include <math.h>

#define Bb 4
#define Cc 8
#define Ss 512
#define Ee 512
#define Hh 8
#define HDd 64
#define NTOK (Bb*Cc*Ss)   // 16384 rows

typedef __attribute__((ext_vector_type(8))) __bf16 bf16x8;
typedef __attribute__((ext_vector_type(4))) float floatx4;
typedef __attribute__((ext_vector_type(4))) unsigned short ushort4v;

__device__ __forceinline__ float bf2f(unsigned short u) {
  union { unsigned int i; float f; } x; x.i = ((unsigned int)u) << 16; return x.f;
}
__device__ __forceinline__ unsigned short f2bf(float f) {
  union { float f; unsigned int i; } x; x.f = f;
  unsigned int r = x.i + 0x7fffu + ((x.i >> 16) & 1u);  // round-to-nearest-even
  return (unsigned short)(r >> 16);
}

// fp32 -> bf16 elementwise, 4 elems/thread, grid-stride
__global__ __launch_bounds__(256) void cvt_f32_bf16(
    const float4* __restrict__ src, ushort4v* __restrict__ dst, int n4)
{
  int idx = blockIdx.x * blockDim.x + threadIdx.x;
  int stride = gridDim.x * blockDim.x;
  for (int i = idx; i < n4; i += stride) {
    float4 v = src[i];
    ushort4v o;
    o[0] = f2bf(v.x); o[1] = f2bf(v.y); o[2] = f2bf(v.z); o[3] = f2bf(v.w);
    dst[i] = o;
  }
}

// out[m,n] = sum_k X[m,k]*W[n,k] + bias[n].  X:[NTOK,512] W:[512,512] bf16, bias fp32.
// blockIdx.x = N-block (8, fastest -> L2 reuse of X), blockIdx.y = M-block (128).
// Block = 256 thr = 4 waves; block tile 128(M)x64(N); wave tile 32x64 = 2x4 MFMA tiles.
template <bool F32OUT>
__global__ __launch_bounds__(256) void gemm_nt_bias(
    const unsigned short* __restrict__ X,
    const unsigned short* __restrict__ W,
    const float* __restrict__ bias,
    void* __restrict__ outv)
{
  const int K = Ee, N = Ee;
  const int lane = threadIdx.x & 63;
  const int wave = threadIdx.x >> 6;
  const int r16  = lane & 15;   // A/B row within 16
  const int oct  = lane >> 4;   // k-octet selector
  const int m_blk = blockIdx.y * 128 + wave * 32;
  const int n_blk = blockIdx.x * 64;

  floatx4 acc[2][4];
  #pragma unroll
  for (int a = 0; a < 2; ++a)
    #pragma unroll
    for (int b = 0; b < 4; ++b)
      acc[a][b] = (floatx4)(0.0f);

  for (int k0 = 0; k0 < K; k0 += 32) {
    const int kk = k0 + oct * 8;
    bf16x8 afr[2], bfr[4];
    #pragma unroll
    for (int mi = 0; mi < 2; ++mi)
      afr[mi] = *(const bf16x8*)(X + (size_t)(m_blk + mi*16 + r16) * K + kk);
    #pragma unroll
    for (int ni = 0; ni < 4; ++ni)
      bfr[ni] = *(const bf16x8*)(W + (size_t)(n_blk + ni*16 + r16) * K + kk);
    #pragma unroll
    for (int mi = 0; mi < 2; ++mi)
      #pragma unroll
      for (int ni = 0; ni < 4; ++ni)
        acc[mi][ni] = __builtin_amdgcn_mfma_f32_16x16x32_bf16(afr[mi], bfr[ni], acc[mi][ni], 0, 0, 0);
  }

  // C/D layout: col = lane&15 (n), row = oct*4 + r (m)
  #pragma unroll
  for (int mi = 0; mi < 2; ++mi)
    #pragma unroll
    for (int ni = 0; ni < 4; ++ni)
      #pragma unroll
      for (int r = 0; r < 4; ++r) {
        const int m = m_blk + mi*16 + oct*4 + r;
        const int n = n_blk + ni*16 + r16;
        const float val = acc[mi][ni][r] + bias[n];
        if (F32OUT) ((float*)outv)[(size_t)m * N + n] = val;
        else        ((unsigned short*)outv)[(size_t)m * N + n] = f2bf(val);
      }
}

// One block (256 thr) per (b,h,c,i) query row.
// Allowed: [i0, i] with i0=max(0,i-32), plus {j%4==0, j<i0}. n <= 153.
__global__ __launch_bounds__(256) void attn_kernel(
    const unsigned short* __restrict__ Q,   // [B,C,S,E] bf16 (ws)
    const unsigned short* __restrict__ Kb,
    const unsigned short* __restrict__ V,
    float* __restrict__ attn_out,           // [B,H,C,S,S] fp32
    unsigned short* __restrict__ ctx)       // [B,C,S,E] bf16 (ws)
{
  const int bid = blockIdx.x;          // (((b*H+h)*C+c)*S + i)
  const int i   = bid & (Ss - 1);
  const int t3  = bid >> 9;
  const int c   = t3 & (Cc - 1);
  const int bh  = t3 >> 3;
  const int h   = bh & (Hh - 1);
  const int b   = bh >> 3;
  const int tid = threadIdx.x;

  __shared__ float qs[HDd];
  __shared__ float pr[Ss];      // full prob row (zeros for masked)
  __shared__ float pv[256];     // normalized probs per list index
  __shared__ int   jl[256];     // column index per list index
  __shared__ float red[256];

  const size_t rowBase = ((size_t)((b*Cc + c)*Ss + i)) * Ee + h * HDd;
  if (tid < HDd) qs[tid] = bf2f(Q[rowBase + tid]);
  pr[tid] = 0.0f; pr[tid + 256] = 0.0f;
  __syncthreads();

  const int i0   = (i > 32) ? (i - 32) : 0;
  const int nStr = (i0 > 0) ? (((i0 - 1) >> 2) + 1) : 0;
  const int n    = nStr + (i - i0 + 1);

  float s = -INFINITY;
  int j = 0;
  if (tid < n) {
    j = (tid < nStr) ? (tid << 2) : (i0 + (tid - nStr));
    jl[tid] = j;
    const unsigned short* krow = Kb + ((size_t)((b*Cc + c)*Ss + j)) * Ee + h * HDd;
    float acc = 0.0f;
    #pragma unroll
    for (int c8 = 0; c8 < 8; ++c8) {
      uint4 u = *(const uint4*)(krow + c8 * 8);
      acc += qs[c8*8+0] * bf2f((unsigned short)(u.x & 0xffffu));
      acc += qs[c8*8+1] * bf2f((unsigned short)(u.x >> 16));
      acc += qs[c8*8+2] * bf2f((unsigned short)(u.y & 0xffffu));
      acc += qs[c8*8+3] * bf2f((unsigned short)(u.y >> 16));
      acc += qs[c8*8+4] * bf2f((unsigned short)(u.z & 0xffffu));
      acc += qs[c8*8+5] * bf2f((unsigned short)(u.z >> 16));
      acc += qs[c8*8+6] * bf2f((unsigned short)(u.w & 0xffffu));
      acc += qs[c8*8+7] * bf2f((unsigned short)(u.w >> 16));
    }
    s = acc * 0.125f;   // 1/sqrt(64)
  }

  red[tid] = s;
  __syncthreads();
  for (int off = 128; off >= 1; off >>= 1) {
    if (tid < off) red[tid] = fmaxf(red[tid], red[tid + off]);
    __syncthreads();
  }
  const float m = red[0];
  __syncthreads();

  float p = (tid < n) ? __expf(s - m) : 0.0f;
  red[tid] = p;
  __syncthreads();
  for (int off = 128; off >= 1; off >>= 1) {
    if (tid < off) red[tid] += red[tid + off];
    __syncthreads();
  }
  const float inv = 1.0f / red[0];
  __syncthreads();

  const float pn = p * inv;
  pv[tid] = pn;
  if (tid < n) pr[j] = pn;
  __syncthreads();

  // write attn row: 512 fp32, 2 per thread (float2)
  {
    float* rowA = attn_out + (size_t)bid * Ss;
    *(float2*)(rowA + 2*tid) = make_float2(pr[2*tid], pr[2*tid + 1]);
  }

  // context: d = tid&63, group g = tid>>6 strides the list
  const int d = tid & 63, g = tid >> 6;
  float accv = 0.0f;
  for (int t = g; t < n; t += 4) {
    const unsigned short* vrow = V + ((size_t)((b*Cc + c)*Ss + jl[t])) * Ee + h * HDd;
    accv += pv[t] * bf2f(vrow[d]);
  }
  __syncthreads();
  red[tid] = accv;
  __syncthreads();
  if (tid < HDd)
    ctx[rowBase + tid] = f2bf(red[tid] + red[tid + 64] + red[tid + 128] + red[tid + 192]);
}

extern "C" void kernel_launch(void* const* d_in, const int* in_sizes, int n_in,
                              void* d_out, int out_size, void* d_ws, size_t ws_size,
                              hipStream_t stream) {
  const float* query = (const float*)d_in[0];
  const float* key_  = (const float*)d_in[1];
  const float* value = (const float*)d_in[2];
  const float* Wq = (const float*)d_in[3];
  const float* bq = (const float*)d_in[4];
  const float* Wk = (const float*)d_in[5];
  const float* bk = (const float*)d_in[6];
  const float* Wv = (const float*)d_in[7];
  const float* bv = (const float*)d_in[8];
  const float* Wo = (const float*)d_in[9];
  const float* bo = (const float*)d_in[10];

  float* out  = (float*)d_out;                          // [B,C,S,E] fp32
  float* attn = out + (size_t)Bb*Cc*Ss*Ee;              // [B,H,C,S,S] fp32

  // ws layout (ushort/bf16)
  unsigned short* ws = (unsigned short*)d_ws;
  unsigned short* qb  = ws;                              // [NTOK,E] bf16 input copies
  unsigned short* kb  = qb  + (size_t)NTOK * Ee;
  unsigned short* vb  = kb  + (size_t)NTOK * Ee;
  unsigned short* Qw  = vb  + (size_t)NTOK * Ee;         // projected Q/K/V
  unsigned short* Kw  = Qw  + (size_t)NTOK * Ee;
  unsigned short* Vw  = Kw  + (size_t)NTOK * Ee;
  unsigned short* Cw  = Vw  + (size_t)NTOK * Ee;         // context
  unsigned short* Wqb = Cw  + (size_t)NTOK * Ee;
  unsigned short* Wkb = Wqb + (size_t)Ee * Ee;
  unsigned short* Wvb = Wkb + (size_t)Ee * Ee;
  unsigned short* Wob = Wvb + (size_t)Ee * Ee;

  const int n4big = NTOK * Ee / 4;   // 2,097,152
  const int n4w   = Ee * Ee / 4;     // 65,536
  cvt_f32_bf16<<<1024, 256, 0, stream>>>((const float4*)query, (ushort4v*)qb, n4big);
  cvt_f32_bf16<<<1024, 256, 0, stream>>>((const float4*)key_,  (ushort4v*)kb, n4big);
  cvt_f32_bf16<<<1024, 256, 0, stream>>>((const float4*)value, (ushort4v*)vb, n4big);
  cvt_f32_bf16<<<256, 256, 0, stream>>>((const float4*)Wq, (ushort4v*)Wqb, n4w);
  cvt_f32_bf16<<<256, 256, 0, stream>>>((const float4*)Wk, (ushort4v*)Wkb, n4w);
  cvt_f32_bf16<<<256, 256, 0, stream>>>((const float4*)Wv, (ushort4v*)Wvb, n4w);
  cvt_f32_bf16<<<256, 256, 0, stream>>>((const float4*)Wo, (ushort4v*)Wob, n4w);

  dim3 blk(256);
  dim3 ggrid(Ee / 64, NTOK / 128);   // x = N-block (fast), y = M-block
  gemm_nt_bias<false><<<ggrid, blk, 0, stream>>>(qb, Wqb, bq, Qw);
  gemm_nt_bias<false><<<ggrid, blk, 0, stream>>>(kb, Wkb, bk, Kw);
  gemm_nt_bias<false><<<ggrid, blk, 0, stream>>>(vb, Wvb, bv, Vw);

  attn_kernel<<<dim3(Bb*Hh*Cc*Ss), blk, 0, stream>>>(Qw, Kw, Vw, attn, Cw);

  gemm_nt_bias<true><<<ggrid, blk, 0, stream>>>(Cw, Wob, bo, out);
}

// Round 3
// 725.163 us; speedup vs baseline: 1.6654x; 1.6654x over previous
//
#include <hip/hip_runtime.h>
#include <math.h>

#define Bb 4
#define Cc 8
#define Ss 512
#define Ee 512
#define Hh 8
#define HDd 64
#define LOCALW 32
#define NTOK (Bb*Cc*Ss)   // 16384 rows

typedef __attribute__((ext_vector_type(8))) __bf16 bf16x8;
typedef __attribute__((ext_vector_type(4))) float floatx4;
typedef __attribute__((ext_vector_type(4))) unsigned short ushort4v;

__device__ __forceinline__ unsigned short f2bf(float f) {
  union { float f; unsigned int i; } x; x.f = f;
  unsigned int r = x.i + 0x7fffu + ((x.i >> 16) & 1u);  // RNE
  return (unsigned short)(r >> 16);
}
__device__ __forceinline__ unsigned int fbits(float f) {
  union { float f; unsigned int i; } x; x.f = f; return x.i;
}

// Convert q,k,v fp32 -> bf16 (blockIdx.y selects tensor)
__global__ __launch_bounds__(256) void cvt3_f32_bf16(
    const float4* __restrict__ s0, const float4* __restrict__ s1, const float4* __restrict__ s2,
    ushort4v* __restrict__ d0, ushort4v* __restrict__ d1, ushort4v* __restrict__ d2, int n4)
{
  const float4* src = (blockIdx.y == 0) ? s0 : (blockIdx.y == 1) ? s1 : s2;
  ushort4v*    dst  = (blockIdx.y == 0) ? d0 : (blockIdx.y == 1) ? d1 : d2;
  int idx = blockIdx.x * blockDim.x + threadIdx.x;
  int stride = gridDim.x * blockDim.x;
  for (int i = idx; i < n4; i += stride) {
    float4 v = src[i];
    ushort4v o;
    o[0] = f2bf(v.x); o[1] = f2bf(v.y); o[2] = f2bf(v.z); o[3] = f2bf(v.w);
    dst[i] = o;
  }
}

// Convert 4 weight matrices fp32 -> bf16
__global__ __launch_bounds__(256) void cvtW_f32_bf16(
    const float4* __restrict__ s0, const float4* __restrict__ s1,
    const float4* __restrict__ s2, const float4* __restrict__ s3,
    ushort4v* __restrict__ d0, ushort4v* __restrict__ d1,
    ushort4v* __restrict__ d2, ushort4v* __restrict__ d3, int n4)
{
  const float4* src = (blockIdx.y == 0) ? s0 : (blockIdx.y == 1) ? s1 : (blockIdx.y == 2) ? s2 : s3;
  ushort4v*    dst  = (blockIdx.y == 0) ? d0 : (blockIdx.y == 1) ? d1 : (blockIdx.y == 2) ? d2 : d3;
  int idx = blockIdx.x * blockDim.x + threadIdx.x;
  int stride = gridDim.x * blockDim.x;
  for (int i = idx; i < n4; i += stride) {
    float4 v = src[i];
    ushort4v o;
    o[0] = f2bf(v.x); o[1] = f2bf(v.y); o[2] = f2bf(v.z); o[3] = f2bf(v.w);
    dst[i] = o;
  }
}

// out[m,n] = sum_k X[m,k]*W[n,k] + bias[n]. Wave tile 64x64 (4x4 MFMA), block 128x128.
template <bool F32OUT>
__global__ __launch_bounds__(256) void gemm_nt_bias(
    const unsigned short* __restrict__ X,
    const unsigned short* __restrict__ W,
    const float* __restrict__ bias,
    void* __restrict__ outv)
{
  const int K = Ee, N = Ee;
  const int lane = threadIdx.x & 63;
  const int wave = threadIdx.x >> 6;
  const int r16  = lane & 15;
  const int oct  = lane >> 4;
  const int m_blk = blockIdx.y * 128 + (wave >> 1) * 64;
  const int n_blk = blockIdx.x * 128 + (wave & 1) * 64;

  floatx4 acc[4][4];
  #pragma unroll
  for (int a = 0; a < 4; ++a)
    #pragma unroll
    for (int b = 0; b < 4; ++b)
      acc[a][b] = (floatx4)(0.0f);

  const unsigned short* Abase = X + (size_t)(m_blk + r16) * K + oct * 8;
  const unsigned short* Bbase = W + (size_t)(n_blk + r16) * K + oct * 8;

  for (int k0 = 0; k0 < K; k0 += 32) {
    bf16x8 af[4], bfq[4];
    #pragma unroll
    for (int mi = 0; mi < 4; ++mi)
      af[mi] = *(const bf16x8*)(Abase + (size_t)mi * 16 * K + k0);
    #pragma unroll
    for (int ni = 0; ni < 4; ++ni)
      bfq[ni] = *(const bf16x8*)(Bbase + (size_t)ni * 16 * K + k0);
    #pragma unroll
    for (int mi = 0; mi < 4; ++mi)
      #pragma unroll
      for (int ni = 0; ni < 4; ++ni)
        acc[mi][ni] = __builtin_amdgcn_mfma_f32_16x16x32_bf16(af[mi], bfq[ni], acc[mi][ni], 0, 0, 0);
  }

  #pragma unroll
  for (int mi = 0; mi < 4; ++mi)
    #pragma unroll
    for (int ni = 0; ni < 4; ++ni)
      #pragma unroll
      for (int r = 0; r < 4; ++r) {
        const int m = m_blk + mi*16 + oct*4 + r;
        const int n = n_blk + ni*16 + r16;
        const float val = acc[mi][ni][r] + bias[n];
        if (F32OUT) ((float*)outv)[(size_t)m * N + n] = val;
        else        ((unsigned short*)outv)[(size_t)m * N + n] = f2bf(val);
      }
}

// One block (512 thr = 8 waves) per (b,h,c) slice. Grid = 256.
// LDS: V^T [64][512] bf16, XOR-swizzled (col stored at j ^ ((d&7)<<3)) = 64 KB.
__global__ __launch_bounds__(512, 2) void attn_kernel(
    const unsigned short* __restrict__ Q,
    const unsigned short* __restrict__ Kb,
    const unsigned short* __restrict__ V,
    float* attn_out,                        // fp32; NOT restrict (re-read for PV)
    unsigned short* __restrict__ ctx)
{
  __shared__ unsigned short VT[HDd][Ss];   // 64 KB

  const int slice = blockIdx.x;            // (b*H + h)*C + c
  const int c  = slice & (Cc - 1);
  const int bh = slice >> 3;
  const int h  = bh & (Hh - 1);
  const int b  = bh >> 3;
  const size_t tokBase  = (size_t)(b * Cc + c) * Ss;
  const size_t attnBase = (size_t)slice * Ss * Ss;

  const int tid  = threadIdx.x;
  const int lane = tid & 63;
  const int wave = tid >> 6;
  const int r16  = lane & 15;
  const int oct  = lane >> 4;

  // ---- stage V^T into LDS (transpose with XOR swizzle) ----
  {
    const int jrow = tid >> 3;        // 0..63
    const int d0   = (tid & 7) * 8;   // 8 d's per thread
    #pragma unroll
    for (int pass = 0; pass < 8; ++pass) {
      const int j = pass * 64 + jrow;
      const uint4 u = *(const uint4*)(V + (tokBase + j) * Ee + h * HDd + d0);
      const unsigned short e[8] = {
        (unsigned short)(u.x & 0xffffu), (unsigned short)(u.x >> 16),
        (unsigned short)(u.y & 0xffffu), (unsigned short)(u.y >> 16),
        (unsigned short)(u.z & 0xffffu), (unsigned short)(u.z >> 16),
        (unsigned short)(u.w & 0xffffu), (unsigned short)(u.w >> 16)};
      #pragma unroll
      for (int k = 0; k < 8; ++k)
        VT[d0 + k][j ^ (k << 3)] = e[k];   // (d0+k)&7 == k
    }
  }
  __syncthreads();

  // ---- per-wave stripes: rt = t*8 + wave ----
  for (int t = 0; t < 4; ++t) {
    const int rt = t * 8 + wave;     // row-tile 0..31
    const int I  = rt * 16;
    const int ibase = I + oct * 4;

    const unsigned short* qrow = Q + (tokBase + I + r16) * Ee + h * HDd + oct * 8;
    const bf16x8 qa0 = *(const bf16x8*)(qrow);
    const bf16x8 qa1 = *(const bf16x8*)(qrow + 32);

    floatx4 sc[32];
    #pragma unroll
    for (int ct = 0; ct < 32; ++ct) {
      if (ct <= rt) {
        const unsigned short* krow = Kb + (tokBase + ct * 16 + r16) * Ee + h * HDd + oct * 8;
        const bf16x8 kb0 = *(const bf16x8*)(krow);
        const bf16x8 kb1 = *(const bf16x8*)(krow + 32);
        floatx4 a = (floatx4)(0.0f);
        a = __builtin_amdgcn_mfma_f32_16x16x32_bf16(qa0, kb0, a, 0, 0, 0);
        a = __builtin_amdgcn_mfma_f32_16x16x32_bf16(qa1, kb1, a, 0, 0, 0);
        sc[ct] = a;
      }
    }

    float mx[4] = {-INFINITY, -INFINITY, -INFINITY, -INFINITY};
    #pragma unroll
    for (int ct = 0; ct < 32; ++ct) {
      if (ct <= rt) {
        #pragma unroll
        for (int r = 0; r < 4; ++r) {
          const int i = ibase + r;
          const int j = ct * 16 + r16;
          const bool allowed = ((j <= i) && (j + LOCALW >= i)) || (((j & 3) == 0) && (j < i));
          const float s = allowed ? sc[ct][r] * 0.125f : -INFINITY;
          sc[ct][r] = s;
          mx[r] = fmaxf(mx[r], s);
        }
      }
    }
    #pragma unroll
    for (int m = 1; m <= 8; m <<= 1)
      #pragma unroll
      for (int r = 0; r < 4; ++r)
        mx[r] = fmaxf(mx[r], __shfl_xor(mx[r], m, 64));

    float sum[4] = {0.0f, 0.0f, 0.0f, 0.0f};
    #pragma unroll
    for (int ct = 0; ct < 32; ++ct) {
      if (ct <= rt) {
        #pragma unroll
        for (int r = 0; r < 4; ++r) {
          const float p = __expf(sc[ct][r] - mx[r]);
          sc[ct][r] = p;
          sum[r] += p;
        }
      }
    }
    #pragma unroll
    for (int m = 1; m <= 8; m <<= 1)
      #pragma unroll
      for (int r = 0; r < 4; ++r)
        sum[r] += __shfl_xor(sum[r], m, 64);
    float inv[4];
    #pragma unroll
    for (int r = 0; r < 4; ++r) inv[r] = 1.0f / sum[r];

    #pragma unroll
    for (int ct = 0; ct < 32; ++ct)
      #pragma unroll
      for (int r = 0; r < 4; ++r) {
        const float p = (ct <= rt) ? sc[ct][r] * inv[r] : 0.0f;
        attn_out[attnBase + (size_t)(ibase + r) * Ss + ct * 16 + r16] = p;
      }

    // ---- PV: P from just-written global attn (L2-hot), B-frags from V^T LDS ----
    floatx4 cacc[4];
    #pragma unroll
    for (int dt = 0; dt < 4; ++dt) cacc[dt] = (floatx4)(0.0f);

    #pragma unroll
    for (int jc = 0; jc < 16; ++jc) {
      if (jc <= (rt >> 1)) {
        const float* prow = attn_out + attnBase + (size_t)(I + r16) * Ss + jc * 32 + oct * 8;
        const float4 p0 = *(const float4*)(prow);
        const float4 p1 = *(const float4*)(prow + 4);
        union { bf16x8 v; unsigned int u[4]; } pa;
        pa.u[0] = (fbits(p0.x) >> 16) | (fbits(p0.y) & 0xffff0000u);
        pa.u[1] = (fbits(p0.z) >> 16) | (fbits(p0.w) & 0xffff0000u);
        pa.u[2] = (fbits(p1.x) >> 16) | (fbits(p1.y) & 0xffff0000u);
        pa.u[3] = (fbits(p1.z) >> 16) | (fbits(p1.w) & 0xffff0000u);
        #pragma unroll
        for (int dt = 0; dt < 4; ++dt) {
          const int d = dt * 16 + r16;
          const int col = (jc * 32 + oct * 8) ^ ((d & 7) << 3);
          const bf16x8 vb = *(const bf16x8*)(&VT[d][col]);
          cacc[dt] = __builtin_amdgcn_mfma_f32_16x16x32_bf16(pa.v, vb, cacc[dt], 0, 0, 0);
        }
      }
    }

    #pragma unroll
    for (int dt = 0; dt < 4; ++dt)
      #pragma unroll
      for (int r = 0; r < 4; ++r)
        ctx[(tokBase + ibase + r) * Ee + h * HDd + dt * 16 + r16] = f2bf(cacc[dt][r]);
  }
}

extern "C" void kernel_launch(void* const* d_in, const int* in_sizes, int n_in,
                              void* d_out, int out_size, void* d_ws, size_t ws_size,
                              hipStream_t stream) {
  const float* query = (const float*)d_in[0];
  const float* key_  = (const float*)d_in[1];
  const float* value = (const float*)d_in[2];
  const float* Wq = (const float*)d_in[3];
  const float* bq = (const float*)d_in[4];
  const float* Wk = (const float*)d_in[5];
  const float* bk = (const float*)d_in[6];
  const float* Wv = (const float*)d_in[7];
  const float* bv = (const float*)d_in[8];
  const float* Wo = (const float*)d_in[9];
  const float* bo = (const float*)d_in[10];

  float* out  = (float*)d_out;                          // [B,C,S,E] fp32
  float* attn = out + (size_t)Bb*Cc*Ss*Ee;              // [B,H,C,S,S] fp32

  unsigned short* ws = (unsigned short*)d_ws;
  unsigned short* qb  = ws;
  unsigned short* kb  = qb  + (size_t)NTOK * Ee;
  unsigned short* vb  = kb  + (size_t)NTOK * Ee;
  unsigned short* Qw  = vb  + (size_t)NTOK * Ee;
  unsigned short* Kw  = Qw  + (size_t)NTOK * Ee;
  unsigned short* Vw  = Kw  + (size_t)NTOK * Ee;
  unsigned short* Cw  = Vw  + (size_t)NTOK * Ee;
  unsigned short* Wqb = Cw  + (size_t)NTOK * Ee;
  unsigned short* Wkb = Wqb + (size_t)Ee * Ee;
  unsigned short* Wvb = Wkb + (size_t)Ee * Ee;
  unsigned short* Wob = Wvb + (size_t)Ee * Ee;

  const int n4big = NTOK * Ee / 4;
  const int n4w   = Ee * Ee / 4;
  cvt3_f32_bf16<<<dim3(1024, 3), 256, 0, stream>>>(
      (const float4*)query, (const float4*)key_, (const float4*)value,
      (ushort4v*)qb, (ushort4v*)kb, (ushort4v*)vb, n4big);
  cvtW_f32_bf16<<<dim3(128, 4), 256, 0, stream>>>(
      (const float4*)Wq, (const float4*)Wk, (const float4*)Wv, (const float4*)Wo,
      (ushort4v*)Wqb, (ushort4v*)Wkb, (ushort4v*)Wvb, (ushort4v*)Wob, n4w);

  dim3 blk(256);
  dim3 ggrid(Ee / 128, NTOK / 128);   // x = N-block (fast), y = M-block
  gemm_nt_bias<false><<<ggrid, blk, 0, stream>>>(qb, Wqb, bq, Qw);
  gemm_nt_bias<false><<<ggrid, blk, 0, stream>>>(kb, Wkb, bk, Kw);
  gemm_nt_bias<false><<<ggrid, blk, 0, stream>>>(vb, Wvb, bv, Vw);

  attn_kernel<<<dim3(Bb*Hh*Cc), 512, 0, stream>>>(Qw, Kw, Vw, attn, Cw);

  gemm_nt_bias<true><<<ggrid, blk, 0, stream>>>(Cw, Wob, bo, out);
}